// Round 8
// baseline (566.188 us; speedup 1.0000x reference)
//
#include <hip/hip_runtime.h>
#include <hip/hip_bf16.h>

#define BDIM 32
#define TDIM 1024
#define HDIM 1024
#define AS1 __attribute__((address_space(1)))
#define AS3 __attribute__((address_space(3)))

typedef __attribute__((ext_vector_type(8))) short short8;
typedef __attribute__((ext_vector_type(8))) unsigned short ushort8;
typedef __attribute__((ext_vector_type(4))) unsigned short u16x4;
typedef __attribute__((ext_vector_type(4))) float f32x4;

__device__ __forceinline__ float b2f(unsigned short h){ return __uint_as_float(((unsigned)h)<<16); }
__device__ __forceinline__ unsigned short f2b(float f){
  unsigned u = __float_as_uint(f);
  u += 0x7fffu + ((u>>16)&1u);
  return (unsigned short)(u>>16);
}
__device__ __forceinline__ float gelu_f(float v){ return 0.5f*v*(1.0f+erff(v*0.70710678118f)); }
__device__ __forceinline__ void stv(float* p, float v){ *p = v; }
__device__ __forceinline__ void stv(unsigned short* p, float v){ *p = f2b(v); }

// ---- convert weights fp32->bf16; tril-mask (incl. diagonal) the temporal ones ----
__global__ void prep_weights(const float* __restrict__ w1, const float* __restrict__ w2,
                             const float* __restrict__ c1, const float* __restrict__ c2,
                             unsigned short* __restrict__ w1m, unsigned short* __restrict__ w2m,
                             unsigned short* __restrict__ c1b, unsigned short* __restrict__ c2b){
  int idx = blockIdx.x*blockDim.x + threadIdx.x;
  int e = idx*4;
  int i = e >> 10, j0 = e & 1023;
  f32x4 a = *(const f32x4*)(w1+e);
  f32x4 b = *(const f32x4*)(w2+e);
  f32x4 c = *(const f32x4*)(c1+e);
  f32x4 d = *(const f32x4*)(c2+e);
  u16x4 av, bv, cv, dv;
  #pragma unroll
  for (int q=0;q<4;++q){
    float am = (j0+q <= i) ? a[q] : 0.f;
    float bm = (j0+q <= i) ? b[q] : 0.f;
    av[q]=f2b(am); bv[q]=f2b(bm); cv[q]=f2b(c[q]); dv[q]=f2b(d[q]);
  }
  *(u16x4*)(w1m+e)=av; *(u16x4*)(w2m+e)=bv; *(u16x4*)(c1b+e)=cv; *(u16x4*)(c2b+e)=dv;
}

// ---- LN1 fused: stats (phase 1) + normalize + transpose (phase 2), 64 t-rows/block ----
__global__ __launch_bounds__(256) void ln1_stats_transpose(
    const float* __restrict__ x, const float* __restrict__ g, const float* __restrict__ bta,
    unsigned short* __restrict__ xnT){
  __shared__ float sm[64], sr[64];
  __shared__ float tile[64][65];
  const int t0 = blockIdx.x*64;
  const int b  = blockIdx.y;
  const int tid = threadIdx.x, wid = tid>>6, lane = tid&63;
  const size_t base = (size_t)b*TDIM*HDIM;
  for (int rr=0; rr<16; ++rr){
    int r = rr*4 + wid;
    const float* pr = x + base + (size_t)(t0+r)*HDIM;
    float s=0.f, s2=0.f;
    #pragma unroll
    for (int it=0; it<4; ++it){
      f32x4 v = *(const f32x4*)(pr + it*256 + lane*4);
      #pragma unroll
      for (int c=0;c<4;++c){ s += v[c]; s2 += v[c]*v[c]; }
    }
    #pragma unroll
    for (int off=32; off>0; off>>=1){ s += __shfl_xor(s,off,64); s2 += __shfl_xor(s2,off,64); }
    if (lane==0){
      float m = s * (1.0f/HDIM);
      sm[r] = m; sr[r] = rsqrtf(s2*(1.0f/HDIM) - m*m + 1e-5f);
    }
  }
  __syncthreads();
  const int rr = tid>>3, c8 = tid&7;
  for (int ht=0; ht<16; ++ht){
    int h0 = ht*64;
    #pragma unroll
    for (int p=0;p<2;++p){
      int r = rr + p*32;
      float m = sm[r], rs = sr[r];
      f32x4 v0 = *(const f32x4*)(x + base + (size_t)(t0+r)*HDIM + h0 + c8*8);
      f32x4 v1 = *(const f32x4*)(x + base + (size_t)(t0+r)*HDIM + h0 + c8*8 + 4);
      #pragma unroll
      for (int c=0;c<4;++c){
        int h = c8*8+c;
        tile[r][h]   = (v0[c]-m)*rs*g[h0+h]   + bta[h0+h];
        tile[r][h+4] = (v1[c]-m)*rs*g[h0+h+4] + bta[h0+h+4];
      }
    }
    __syncthreads();
    #pragma unroll
    for (int p=0;p<2;++p){
      int hr = rr + p*32;
      ushort8 ov;
      #pragma unroll
      for (int c=0;c<8;++c) ov[c] = f2b(tile[c8*8+c][hr]);
      *(ushort8*)(xnT + base + (size_t)(h0+hr)*TDIM + t0 + c8*8) = ov;
    }
    __syncthreads();
  }
}

// ---- LN2 fused single-pass: bf16 in, bf16 out ----
__global__ void ln_fused(const unsigned short* __restrict__ p, const float* __restrict__ g,
                         const float* __restrict__ bta, unsigned short* __restrict__ o){
  int wid = threadIdx.x>>6, lane = threadIdx.x&63;
  size_t row = (size_t)blockIdx.x*4 + wid;
  const unsigned short* pr = p + row*HDIM + lane*16;
  ushort8 v0 = *(const ushort8*)(pr);
  ushort8 v1 = *(const ushort8*)(pr+8);
  float f[16];
  float s=0.f, s2=0.f;
  #pragma unroll
  for (int c=0;c<8;++c){ f[c]=b2f(v0[c]); f[c+8]=b2f(v1[c]); }
  #pragma unroll
  for (int c=0;c<16;++c){ s += f[c]; s2 += f[c]*f[c]; }
  #pragma unroll
  for (int off=32; off>0; off>>=1){ s += __shfl_xor(s,off,64); s2 += __shfl_xor(s2,off,64); }
  float m = s * (1.0f/HDIM);
  float rs = rsqrtf(s2*(1.0f/HDIM) - m*m + 1e-5f);
  int h0 = lane*16;
  ushort8 o0, o1;
  #pragma unroll
  for (int c=0;c<8;++c){
    o0[c] = f2b((f[c]-m)*rs*g[h0+c] + bta[h0+c]);
    o1[c] = f2b((f[c+8]-m)*rs*g[h0+c+8] + bta[h0+c+8]);
  }
  *(ushort8*)(o + row*HDIM + h0) = o0;
  *(ushort8*)(o + row*HDIM + h0 + 8) = o1;
}

// ======== 256x256 BK=64, 8-wave, 2-fat-phase pipelined GEMM, 1 block/CU x 2 reps ========
// C[m,n] = sum_k A[m,k]*B[n,k], both K-major bf16.
// Per K-tile: P0 computes rows 0-127 (A0 x all B), P1 rows 128-255 (A1, bR reused in regs).
// Wave grid 2x4: per wave per phase 64x64 output = 32 MFMA; reads: P0 16x b128, P1 8x b128.
// LDS 144KB: A0 x2 slots [0,32K), A1 x3 slots [32K,80K), B0 x2 [80K,112K), B1 x2 [112K,144K).
// Stage: all 4 halves of tile t+2 batched in P1(t), A1 LAST. FIFO gates: GATE(8)@P0 forces
// A1(t) landed; GATE(10)@P1 forces A0/B0/B1(t+1) landed (leaves A1(t+1)+batch(t+2) in flight).
// Tail: clamped dummy stages keep vmcnt counts exact. One block per CU; 2 sub-GEMMs (reps)
// per block: temporal reps pair inners {i0,3-i0} (uniform 20 K-subtiles), channel {2i0,2i0+1}.
#define GATE(N) asm volatile("s_waitcnt vmcnt(" #N ")" ::: "memory")
#define BAR()   __builtin_amdgcn_s_barrier()

template<int MODE, typename CT, typename RT>
__global__ __launch_bounds__(512,2)
void gemm2p(const unsigned short* __restrict__ act, const unsigned short* __restrict__ wgt,
            CT* __restrict__ C, const float* __restrict__ bias, const RT* __restrict__ resid){
  extern __shared__ char LDS[];
  const int bid = blockIdx.x;
  const int pair = (bid & 7)*32 + (bid >> 3);     // XCD-chunked
  const int panel = pair >> 1;
  const int tid = threadIdx.x, lane = tid&63, wid = tid>>6;
  const int wrow = (wid>>2)*64;                   // A-row base within 128-row half
  const int wcol = (wid&3)*64;                    // C-col base within 256
  const int l15 = lane&15, l4b = (lane>>4)<<4;
  const int bhalf = wcol >> 7;                    // which B half this wave reads
  const int brow0 = wcol & 127;

  for (int rep=0; rep<2; ++rep){
    int inner;
    if constexpr (MODE==1 || MODE==2){
      int i0 = pair & 1;
      inner = rep ? (3-i0) : i0;
    } else {
      inner = (pair&1)*2 + rep;
    }
    const unsigned short *pa, *pb;
    size_t cbase; int rg0, cg0, kend;
    if constexpr (MODE==1){
      int b = panel>>2, mt = panel&3;
      pa = act + (size_t)b*1048576 + (size_t)mt*262144;
      pb = wgt + (size_t)inner*262144;
      kend = (inner+1)*256;
      cbase = (size_t)b*1048576; rg0 = mt*256; cg0 = inner*256;
    } else if constexpr (MODE==2){
      int b = panel>>2, nt = panel&3;
      pa = wgt + (size_t)inner*262144;
      pb = act + (size_t)b*1048576 + (size_t)nt*262144;
      kend = (inner+1)*256;
      cbase = (size_t)b*1048576; rg0 = inner*256; cg0 = nt*256;
    } else {
      pa = act + (size_t)panel*262144;
      pb = wgt + (size_t)inner*262144;
      kend = 1024;
      cbase = 0; rg0 = panel*256; cg0 = inner*256;
    }
    const int NT = kend >> 6;

    auto stage2 = [&](int dstoff, const unsigned short* src, int rbase, int k0){
      #pragma unroll
      for (int l=0;l<2;++l){
        int W = tid*16 + (l<<13);
        int r = W>>7;
        int cs = (W&127) ^ ((r&7)<<4);            // inverse swizzle on global source
        __builtin_amdgcn_global_load_lds(
          (const AS1 void*)(src + (size_t)(rbase+r)*1024 + k0 + (cs>>1)),
          (AS3 void*)(LDS + dstoff + W), 16, 0, 0);
      }
    };
    auto BATCH = [&](int tt, int a1slot){
      int st = tt < NT ? tt : NT-1;
      int k0 = st << 6;
      int bp = (tt&1)*16384;
      stage2(bp,                    pa, 0,   k0);   // A0
      stage2(81920 + bp,            pb, 0,   k0);   // B0
      stage2(114688 + bp,           pb, 128, k0);   // B1
      stage2(32768 + a1slot*16384,  pa, 128, k0);   // A1 LAST (later deadline)
    };
    auto LDA = [&](int base, int i, int s)->short8{
      int ra = wrow + i*16 + l15;
      int L = (ra<<7) + (((s<<6) + l4b) ^ ((ra&7)<<4));
      return *(const short8*)(LDS + base + L);
    };
    auto LDB = [&](int bp, int j, int s)->short8{
      int rb = brow0 + j*16 + l15;
      int L = (rb<<7) + (((s<<6) + l4b) ^ ((rb&7)<<4));
      return *(const short8*)(LDS + (bhalf ? 114688 : 81920) + bp + L);
    };

    f32x4 acc[8][4];
    #pragma unroll
    for (int i=0;i<8;++i)
      #pragma unroll
      for (int j=0;j<4;++j) acc[i][j] = (f32x4)(0.f);

#define MFMAH(Ih)                                                              \
    __builtin_amdgcn_s_setprio(1);                                             \
    _Pragma("unroll") for (int s=0;s<2;++s)                                    \
      _Pragma("unroll") for (int i=0;i<4;++i)                                  \
        _Pragma("unroll") for (int j=0;j<4;++j)                                \
          acc[(Ih)*4+i][j] = __builtin_amdgcn_mfma_f32_16x16x32_bf16(          \
              aR[s][i], bR[s][j], acc[(Ih)*4+i][j], 0,0,0);                    \
    __builtin_amdgcn_s_setprio(0);

    // prologue: tiles 0 and 1 fully staged; force tile0's A0/B0/B1 (A1 forced by P0 gate)
    BATCH(0, 0); BATCH(1, 1);
    GATE(10); BAR();

    int s1 = 0, s1n2 = 2;
    short8 aR[2][4], bR[2][4];
    for (int t=0; t<NT; ++t){
      const int bp = (t&1)*16384;
      // ---- P0: rows 0-127. read A0 + B(both halves per-wave slice); gate A1(t)
      #pragma unroll
      for (int s=0;s<2;++s){
        #pragma unroll
        for (int i=0;i<4;++i) aR[s][i] = LDA(bp, i, s);
        #pragma unroll
        for (int j=0;j<4;++j) bR[s][j] = LDB(bp, j, s);
      }
      GATE(8); BAR();
      MFMAH(0)
      BAR();
      // ---- P1: rows 128-255. read A1 (bR reused); stage batch(t+2); gate batch(t+1) core
      #pragma unroll
      for (int s=0;s<2;++s)
        #pragma unroll
        for (int i=0;i<4;++i) aR[s][i] = LDA(32768 + s1*16384, i, s);
      BATCH(t+2, s1n2);
      GATE(10); BAR();
      MFMAH(1)
      BAR();
      s1   = (s1  ==2) ? 0 : s1+1;
      s1n2 = (s1n2==2) ? 0 : s1n2+1;
    }
#undef MFMAH

    // epilogue: acc[Ih*4+i][j]; frag row=(lane>>4)*4+r, col=lane&15
    #pragma unroll
    for (int I=0;I<8;++I){
      int rbase = rg0 + (I>>2)*128 + wrow + (I&3)*16 + ((lane>>4)<<2);
      #pragma unroll
      for (int J=0;J<4;++J){
        int cg = cg0 + wcol + J*16 + l15;
        float bn = (MODE!=2) ? bias[cg] : 0.f;
        #pragma unroll
        for (int r=0;r<4;++r){
          int rg = rbase + r;
          float v = acc[I][J][r];
          if (MODE==1 || MODE==3){ v += bn; v = gelu_f(v); }
          else if (MODE==2){ v += bias[rg]; v += resid[cbase + (size_t)rg*1024 + cg]; }
          else { v += bn; v += b2f(resid[cbase + (size_t)rg*1024 + cg]); }
          stv(&C[cbase + (size_t)rg*1024 + cg], v);
        }
      }
    }
    // drain all DMA (incl. tail dummies) before rep+1 overwrites LDS slots
    GATE(0); BAR();
  }
}

extern "C" void kernel_launch(void* const* d_in, const int* in_sizes, int n_in,
                              void* d_out, int out_size, void* d_ws, size_t ws_size,
                              hipStream_t stream){
  const float* x    = (const float*)d_in[0];
  const float* tw1  = (const float*)d_in[1];
  const float* tb1  = (const float*)d_in[2];
  const float* tw2  = (const float*)d_in[3];
  const float* tb2  = (const float*)d_in[4];
  const float* cw1  = (const float*)d_in[5];
  const float* cb1  = (const float*)d_in[6];
  const float* cw2  = (const float*)d_in[7];
  const float* cb2  = (const float*)d_in[8];
  const float* g1   = (const float*)d_in[9];
  const float* bb1  = (const float*)d_in[10];
  const float* g2   = (const float*)d_in[11];
  const float* bb2  = (const float*)d_in[12];
  float* out = (float*)d_out;

  char* ws = (char*)d_ws;
  unsigned short* bufA = (unsigned short*)(ws);                    // 64MB bf16
  unsigned short* bufB = (unsigned short*)(ws + 67108864);         // 64MB bf16
  unsigned short* xmid = (unsigned short*)(ws + 134217728);        // 64MB bf16 x_mid
  unsigned short* w1m  = (unsigned short*)(ws + 201326592);        // 2MB
  unsigned short* w2m  = (unsigned short*)(ws + 203423744);        // 2MB
  unsigned short* c1b  = (unsigned short*)(ws + 205520896);        // 2MB
  unsigned short* c2b  = (unsigned short*)(ws + 207618048);        // 2MB

  prep_weights<<<1024,256,0,stream>>>(tw1,tw2,cw1,cw2,w1m,w2m,c1b,c2b);
  // temporal path
  ln1_stats_transpose<<<dim3(16,32),256,0,stream>>>(x, g1, bb1, bufA);
  gemm2p<1,unsigned short,float><<<256,512,147456,stream>>>(bufA, w1m, bufB, tb1, (const float*)nullptr);
  gemm2p<2,unsigned short,float><<<256,512,147456,stream>>>(bufB, w2m, xmid, tb2, x);
  // channel path
  ln_fused<<<8192,256,0,stream>>>(xmid, g2, bb2, bufA);
  gemm2p<3,unsigned short,unsigned short><<<256,512,147456,stream>>>(bufA, c1b, bufB, cb1, (const unsigned short*)nullptr);
  gemm2p<4,float,unsigned short><<<256,512,147456,stream>>>(bufB, c2b, out, cb2, xmid);
}